// Round 3
// baseline (278.999 us; speedup 1.0000x reference)
//
#include <hip/hip_runtime.h>

// CoupleLoss: protos = id_prototypes with rows[label] := teachor_ftr (last write
// wins on duplicate labels = numpy semantics), gi = protos[idH[label,:K]],
// loss = mean(relu(dot(gi, ftr - teachor_ftr) - MARGIN))
// (smrs - tmrs = dot(gi, ftr - teachor)).
//
// R3: same one-block-per-b structure as R2, but the gather runs in 3 rounds of
// 9/8/8 rows (18 float4 in flight per wave instead of 10, fewer dependent
// latency rounds), and the ftr/tftr loads are issued before the prologue
// barrier so they overlap the bitmap build.

#define NUM_IDS 100000
#define FEAT    512
#define BATCH   512
#define KNEG    100
#define MARGIN  0.03f
#define NBM     ((NUM_IDS + 31) / 32)   // 3125 u32 = 12.5 KB

__device__ __forceinline__ float dot8(float4 a, float4 c, float4 da, float4 db) {
    return a.x*da.x + a.y*da.y + a.z*da.z + a.w*da.w
         + c.x*db.x + c.y*db.y + c.z*db.z + c.w*db.w;
}

__global__ __launch_bounds__(256, 2) void couple_main(
    const float* __restrict__ ftr,
    const float* __restrict__ tftr,
    const int*   __restrict__ label,
    const float* __restrict__ protos,
    const int*   __restrict__ idH,
    float*       __restrict__ bsums)
{
    __shared__ unsigned bm[NBM];
    __shared__ int   ls[BATCH];
    __shared__ int   rowsrc[KNEG];
    __shared__ float wsum[4];

    const int t    = threadIdx.x;
    const int lane = t & 63;
    const int wave = t >> 6;
    const int b    = blockIdx.x;

    // Issue the per-b feature loads FIRST so they overlap the prologue.
    const float4* f4 = (const float4*)(ftr  + (size_t)b * FEAT);
    const float4* t4 = (const float4*)(tftr + (size_t)b * FEAT);
    float4 fa = f4[lane], fb = f4[lane + 64];
    float4 ta = t4[lane], tb = t4[lane + 64];

    // Stage labels into LDS; clear bitmap.
    ls[t]       = label[t];
    ls[t + 256] = label[t + 256];
    for (int i = t; i < NBM; i += 256) bm[i] = 0u;
    __syncthreads();
    {
        int l0 = ls[t], l1 = ls[t + 256];
        atomicOr(&bm[l0 >> 5], 1u << (l0 & 31));
        atomicOr(&bm[l1 >> 5], 1u << (l1 & 31));
    }
    const int myl = label[b];   // wave-uniform scalar load
    __syncthreads();

    // Resolve the 100 neg sources. src >= 0 -> tftr row src (id overwritten;
    // src = max batch idx with that label = numpy last-write-wins);
    // src < 0 -> protos row (~src).
    if (t < KNEG) {
        int nid = idH[myl * KNEG + t];
        int src = ~nid;
        if (bm[nid >> 5] & (1u << (nid & 31))) {     // rare (~0.5 per block)
            int m = -1;
            const int4* l4 = (const int4*)ls;
            #pragma unroll 4
            for (int j = 0; j < BATCH / 4; ++j) {
                int4 v = l4[j];
                if (v.x == nid) m = 4*j;
                if (v.y == nid) m = 4*j + 1;
                if (v.z == nid) m = 4*j + 2;
                if (v.w == nid) m = 4*j + 3;
            }
            src = m;
        }
        rowsrc[t] = src;
    }

    float4 da = {fa.x - ta.x, fa.y - ta.y, fa.z - ta.z, fa.w - ta.w};
    float4 db = {fb.x - tb.x, fb.y - tb.y, fb.z - tb.z, fb.w - tb.w};
    __syncthreads();

    // Each wave: 25 contiguous k's in 3 rounds of 9/8/8 (18/16 float4 loads in
    // flight per wave per round).
    float acc = 0.0f;
    const int kbase = wave * 25;
    #pragma unroll
    for (int r = 0; r < 3; ++r) {
        const int nrows = (r == 0) ? 9 : 8;
        const int kk = kbase + ((r == 0) ? 0 : 9 + (r - 1) * 8);

        const float4* g[9];
        #pragma unroll
        for (int u = 0; u < 9; ++u) {
            if (u < nrows) {
                int s = rowsrc[kk + u];
                g[u] = (s >= 0) ? (const float4*)(tftr   + (size_t)s    * FEAT)
                                : (const float4*)(protos + (size_t)(~s) * FEAT);
            }
        }
        float4 a[9], c[9];
        #pragma unroll
        for (int u = 0; u < 9; ++u) {
            if (u < nrows) { a[u] = g[u][lane]; c[u] = g[u][lane + 64]; }
        }
        float s[9];
        #pragma unroll
        for (int u = 0; u < 9; ++u) {
            if (u < nrows) s[u] = dot8(a[u], c[u], da, db);
        }
        #pragma unroll
        for (int off = 32; off >= 1; off >>= 1) {   // interleaved butterflies
            #pragma unroll
            for (int u = 0; u < 9; ++u) {
                if (u < nrows) s[u] += __shfl_xor(s[u], off, 64);
            }
        }
        #pragma unroll
        for (int u = 0; u < 9; ++u) {
            if (u < nrows) acc += fmaxf(s[u] - MARGIN, 0.0f);
        }
    }

    if (lane == 0) wsum[wave] = acc;
    __syncthreads();
    if (t == 0) bsums[b] = wsum[0] + wsum[1] + wsum[2] + wsum[3];
}

// Reduce 512 per-block sums -> mean. One block, 256 threads.
__global__ __launch_bounds__(256) void couple_finalize(
    const float* __restrict__ bsums, float* __restrict__ out)
{
    const int t = threadIdx.x;
    float v = bsums[t] + bsums[t + 256];
    #pragma unroll
    for (int off = 32; off >= 1; off >>= 1) v += __shfl_xor(v, off, 64);
    __shared__ float w[4];
    if ((t & 63) == 0) w[t >> 6] = v;
    __syncthreads();
    if (t == 0) out[0] = (w[0] + w[1] + w[2] + w[3]) * (1.0f / (BATCH * KNEG));
}

extern "C" void kernel_launch(void* const* d_in, const int* in_sizes, int n_in,
                              void* d_out, int out_size, void* d_ws, size_t ws_size,
                              hipStream_t stream) {
    const float* ftr    = (const float*)d_in[0];
    const float* tftr   = (const float*)d_in[1];
    const int*   label  = (const int*)d_in[2];
    const float* protos = (const float*)d_in[3];
    const int*   idH    = (const int*)d_in[4];
    float* out   = (float*)d_out;
    float* bsums = (float*)d_ws;   // 512 floats of scratch (no init needed)

    (void)in_sizes; (void)n_in; (void)out_size; (void)ws_size;

    couple_main<<<BATCH, 256, 0, stream>>>(ftr, tftr, label, protos, idH, bsums);
    couple_finalize<<<1, 256, 0, stream>>>(bsums, out);
}